// Round 3
// baseline (880.755 us; speedup 1.0000x reference)
//
#include <hip/hip_runtime.h>
#include <hip/hip_bf16.h>

// Attention layer: B=2, S=2048, H=2048, NH=16, NKV=4, HD=128, N_REP=4
// cvt X->bf16; transpose weights; fused QKV GEMM (glds+dbuf); RoPE (scale*log2e
// folded into Q); V transpose; balanced strip-pair causal flash attention with
// swapped QK^T + in-lane softmax; O-proj GEMM (f32 out).

typedef __bf16 bf16;
typedef __bf16 bf16x8 __attribute__((ext_vector_type(8)));
typedef __bf16 bf16x4 __attribute__((ext_vector_type(4)));
typedef float  f32x4  __attribute__((ext_vector_type(4)));

#define MFMA_BF16(a, b, c) __builtin_amdgcn_mfma_f32_16x16x32_bf16((a), (b), (c), 0, 0, 0)

__device__ __forceinline__ void glds16(const bf16* g, char* l) {
  __builtin_amdgcn_global_load_lds((__attribute__((address_space(1))) const void*)g,
                                   (__attribute__((address_space(3))) void*)l, 16, 0, 0);
}

// ------------------------------------------------------------------
__global__ __launch_bounds__(256) void k_cvt_bf16(const float* __restrict__ in,
                                                  bf16* __restrict__ out, int n4) {
  int i = blockIdx.x * 256 + threadIdx.x;
  if (i < n4) {
    float4 v = ((const float4*)in)[i];
    bf16x4 o;
    o[0] = (bf16)v.x; o[1] = (bf16)v.y; o[2] = (bf16)v.z; o[3] = (bf16)v.w;
    ((bf16x4*)out)[i] = o;
  }
}

// ------------------------------------------------------------------
// W [Kd][N] f32  ->  Wt [N][Kd] bf16
__global__ __launch_bounds__(256) void k_transpose_w(const float* __restrict__ W,
                                                     bf16* __restrict__ Wt, int Kd, int N) {
  __shared__ float tile[32][33];
  int tx = threadIdx.x, ty = threadIdx.y;
  int kb = blockIdx.x * 32, nb = blockIdx.y * 32;
#pragma unroll
  for (int i = 0; i < 4; ++i)
    tile[ty + i * 8][tx] = W[(size_t)(kb + ty + i * 8) * N + nb + tx];
  __syncthreads();
#pragma unroll
  for (int i = 0; i < 4; ++i)
    Wt[(size_t)(nb + ty + i * 8) * Kd + kb + tx] = (bf16)tile[tx][ty + i * 8];
}

// ------------------------------------------------------------------
// V [4096][512] bf16 -> Vt [(b*4+kv)*128 + d][2048] bf16
__global__ __launch_bounds__(256) void k_transpose_v(const bf16* __restrict__ V,
                                                     bf16* __restrict__ Vt) {
  __shared__ bf16 tile[32][33];
  int tx = threadIdx.x, ty = threadIdx.y;
  int b = blockIdx.z;
  int sb = blockIdx.x * 32, cb = blockIdx.y * 32;
#pragma unroll
  for (int i = 0; i < 4; ++i)
    tile[ty + i * 8][tx] = V[(size_t)(b * 2048 + sb + ty + i * 8) * 512 + cb + tx];
  __syncthreads();
#pragma unroll
  for (int i = 0; i < 4; ++i)
    Vt[(size_t)(b * 512 + cb + ty + i * 8) * 2048 + sb + tx] = tile[tx][ty + i * 8];
}

// ------------------------------------------------------------------
// RoPE in-place; scl folds softmax scale*log2e into Q (1.0 for K).
__global__ __launch_bounds__(256) void k_rope(bf16* __restrict__ T,
                                              const float* __restrict__ cosb,
                                              const float* __restrict__ sinb,
                                              int ncols, float scl) {
  int i = blockIdx.x * 256 + threadIdx.x;
  int npr = ncols >> 1;
  int row = i / npr;
  int p = i - row * npr;
  int h = p >> 6, d = p & 63;
  int c0 = h * 128 + d;
  size_t base = (size_t)row * ncols;
  int s = row & 2047;
  float q0 = (float)T[base + c0];
  float q1 = (float)T[base + c0 + 64];
  float vc0 = cosb[s * 128 + d],      vc1 = cosb[s * 128 + d + 64];
  float vs0 = sinb[s * 128 + d],      vs1 = sinb[s * 128 + d + 64];
  T[base + c0]      = (bf16)((q0 * vc0 - q1 * vs0) * scl);
  T[base + c0 + 64] = (bf16)((q1 * vc1 + q0 * vs1) * scl);
}

// ------------------------------------------------------------------
// GEMM 128x128 tile, BK=64, global_load_lds staging (inverse-swizzled source),
// double-buffered LDS, one barrier per K-step.
template <typename OUT>
__device__ void gemm_block(const bf16* __restrict__ A, const bf16* __restrict__ Bt,
                           OUT* __restrict__ C, int K, int ldc,
                           int rbase, int cbase, char* sm) {
  const int tid = threadIdx.x;
  const int lane = tid & 63, wid = tid >> 6;
  const int l15 = lane & 15, lg = lane >> 4;
  char* Asm = sm;            // 2 x 16KB : [128][128B] swizzled
  char* Bsm = sm + 32768;    // 2 x 16KB

  f32x4 acc[2][8];
#pragma unroll
  for (int i = 0; i < 2; ++i)
#pragma unroll
    for (int j = 0; j < 8; ++j)
#pragma unroll
      for (int r = 0; r < 4; ++r) acc[i][j][r] = 0.0f;

  const int ob = wid * 4096 + lane * 16;
  auto stage = [&](int buf, int kb) {
#pragma unroll
    for (int c = 0; c < 4; ++c) {
      int o = ob + c * 1024;
      int r = o >> 7;
      int cc = ((o >> 4) & 7) ^ (r & 7);
      int dst = wid * 4096 + c * 1024 + buf * 16384;   // wave-uniform LDS base
      glds16(A + (size_t)(rbase + r) * K + kb + cc * 8, Asm + dst);
      glds16(Bt + (size_t)(cbase + r) * K + kb + cc * 8, Bsm + dst);
    }
  };

  stage(0, 0);
  __syncthreads();
  const int nk = K >> 6;
  for (int t = 0; t < nk; ++t) {
    if (t + 1 < nk) stage((t + 1) & 1, (t + 1) << 6);
    const char* At  = Asm + (t & 1) * 16384;
    const char* Bti = Bsm + (t & 1) * 16384;
#pragma unroll
    for (int ks = 0; ks < 2; ++ks) {
      bf16x8 a[2], b[8];
#pragma unroll
      for (int rf = 0; rf < 2; ++rf) {
        int r = wid * 32 + rf * 16 + l15;
        int slot = (ks * 4 + lg) ^ (r & 7);
        a[rf] = *(const bf16x8*)(At + r * 128 + slot * 16);
      }
#pragma unroll
      for (int nf = 0; nf < 8; ++nf) {
        int n = nf * 16 + l15;
        int slot = (ks * 4 + lg) ^ (n & 7);
        b[nf] = *(const bf16x8*)(Bti + n * 128 + slot * 16);
      }
#pragma unroll
      for (int rf = 0; rf < 2; ++rf)
#pragma unroll
        for (int nf = 0; nf < 8; ++nf)
          acc[rf][nf] = MFMA_BF16(a[rf], b[nf], acc[rf][nf]);
    }
    __syncthreads();
  }

#pragma unroll
  for (int rf = 0; rf < 2; ++rf)
#pragma unroll
    for (int nf = 0; nf < 8; ++nf)
#pragma unroll
      for (int r = 0; r < 4; ++r) {
        int row = rbase + wid * 32 + rf * 16 + lg * 4 + r;
        int col = cbase + nf * 16 + l15;
        C[(size_t)row * ldc + col] = (OUT)acc[rf][nf][r];
      }
}

__global__ __launch_bounds__(256, 2) void k_gemm_qkv(const bf16* __restrict__ X,
                                                     const bf16* __restrict__ Wtq,
                                                     const bf16* __restrict__ Wtk,
                                                     const bf16* __restrict__ Wtv,
                                                     bf16* __restrict__ Q,
                                                     bf16* __restrict__ Ko,
                                                     bf16* __restrict__ Vo) {
  __shared__ alignas(16) char sm[65536];
  int nb = blockIdx.y;
  int rbase = blockIdx.x * 128;
  const bf16* Bt; bf16* C; int ldc, cbase;
  if (nb < 16)      { Bt = Wtq; C = Q;  ldc = 2048; cbase = nb * 128; }
  else if (nb < 20) { Bt = Wtk; C = Ko; ldc = 512;  cbase = (nb - 16) * 128; }
  else              { Bt = Wtv; C = Vo; ldc = 512;  cbase = (nb - 20) * 128; }
  gemm_block<bf16>(X, Bt, C, 2048, ldc, rbase, cbase, sm);
}

__global__ __launch_bounds__(256, 2) void k_gemm_o(const bf16* __restrict__ AO,
                                                   const bf16* __restrict__ Wto,
                                                   float* __restrict__ Out) {
  __shared__ alignas(16) char sm[65536];
  gemm_block<float>(AO, Wto, Out, 2048, 2048, blockIdx.x * 128, blockIdx.y * 128, sm);
}

// ------------------------------------------------------------------
// Balanced causal flash attention. Block = strip pair (iA=x, iB=31-x), strips
// of 64 q-rows; 4 waves x 16 rows per strip. Swapped QK^T (S^T layout) ->
// in-lane softmax. K/V double-buffered via global_load_lds; 1 barrier/tile.
__global__ __launch_bounds__(256, 2) void k_fattn(const bf16* __restrict__ Qg,
                                                  const bf16* __restrict__ Kg,
                                                  const bf16* __restrict__ Vtg,
                                                  bf16* __restrict__ AO) {
  __shared__ alignas(16) char sm[81920];
  // [0,32768): K 2x(64x256B) ; [32768,65536): Vt 2x(128x128B) ; [65536,81920): P 4x4KB
  const int lane = threadIdx.x & 63, wid = threadIdx.x >> 6;
  const int l15 = lane & 15, lg = lane >> 4;
  const int b = blockIdx.z, h = blockIdx.y, kv = h >> 2;
  const int iA = blockIdx.x, iB = 31 - iA;
  const int qA0 = iA * 64 + wid * 16, qB0 = iB * 64 + wid * 16;
  const int kendA = iA * 64 + 64;
  const int nt = iB + 1;
  char* Pw = sm + 65536 + wid * 4096;   // strip A at +0 (2KB), strip B at +2048

  bf16x8 qfA[4], qfB[4];
#pragma unroll
  for (int kf = 0; kf < 4; ++kf) {
    qfA[kf] = *(const bf16x8*)(Qg + (size_t)(b * 2048 + qA0 + l15) * 2048 + h * 128 + kf * 32 + lg * 8);
    qfB[kf] = *(const bf16x8*)(Qg + (size_t)(b * 2048 + qB0 + l15) * 2048 + h * 128 + kf * 32 + lg * 8);
  }

  f32x4 oA[8], oB[8];
#pragma unroll
  for (int j = 0; j < 8; ++j)
#pragma unroll
    for (int r = 0; r < 4; ++r) { oA[j][r] = 0.0f; oB[j][r] = 0.0f; }
  float mA = -3e38f, lA = 0.0f, mB = -3e38f, lB = 0.0f;

  const int ob = wid * 4096 + lane * 16;
  auto stageKV = [&](int buf, int kb) {
#pragma unroll
    for (int c = 0; c < 4; ++c) {
      int o = ob + c * 1024;
      {
        int r = o >> 8;                      // 0..63
        int slot = (o >> 4) & 15;
        int cc = slot ^ (r & 7);
        glds16(Kg + (size_t)(b * 2048 + kb + r) * 512 + kv * 128 + cc * 8,
               sm + buf * 16384 + wid * 4096 + c * 1024);
      }
      {
        int r = o >> 7;                      // 0..127
        int slot = (o >> 4) & 7;
        int cc = slot ^ (r & 7);
        glds16(Vtg + (size_t)((b * 4 + kv) * 128 + r) * 2048 + kb + cc * 8,
               sm + 32768 + buf * 16384 + wid * 4096 + c * 1024);
      }
    }
  };

  stageKV(0, 0);
  __syncthreads();

  for (int t = 0; t < nt; ++t) {
    const int kb = t << 6;
    if (t + 1 < nt) stageKV((t + 1) & 1, kb + 64);
    const char* Kt = sm + (t & 1) * 16384;
    const char* Vt = sm + 32768 + (t & 1) * 16384;
    const bool actA = kb < kendA;

    f32x4 saA[4], saB[4];
#pragma unroll
    for (int j = 0; j < 4; ++j)
#pragma unroll
      for (int r = 0; r < 4; ++r) { saA[j][r] = 0.0f; saB[j][r] = 0.0f; }

#pragma unroll
    for (int ks = 0; ks < 4; ++ks) {
      bf16x8 bk[4];
#pragma unroll
      for (int nf = 0; nf < 4; ++nf) {
        int n = nf * 16 + l15;
        int slot = (ks * 4 + lg) ^ (n & 7);
        bk[nf] = *(const bf16x8*)(Kt + n * 256 + slot * 16);
      }
#pragma unroll
      for (int nf = 0; nf < 4; ++nf)
        saB[nf] = MFMA_BF16(bk[nf], qfB[ks], saB[nf]);
      if (actA) {
#pragma unroll
        for (int nf = 0; nf < 4; ++nf)
          saA[nf] = MFMA_BF16(bk[nf], qfA[ks], saA[nf]);
      }
    }

    // softmax (values already in log2 units): lane owns one q-row (qi=q0+l15)
    auto sfm = [&](f32x4* sa, float& mrun, float& lrun, f32x4* o, int q0, char* Pb) {
      if (kb + 63 > q0) {
        const int qi = q0 + l15;
#pragma unroll
        for (int nf = 0; nf < 4; ++nf)
#pragma unroll
          for (int r = 0; r < 4; ++r)
            if (kb + nf * 16 + lg * 4 + r > qi) sa[nf][r] = -3e38f;
      }
      float mx = sa[0][0];
#pragma unroll
      for (int nf = 0; nf < 4; ++nf)
#pragma unroll
        for (int r = 0; r < 4; ++r) mx = fmaxf(mx, sa[nf][r]);
      mx = fmaxf(mx, __shfl_xor(mx, 16));
      mx = fmaxf(mx, __shfl_xor(mx, 32));
      if (!__all(mx - mrun <= 8.0f)) {       // defer-max (THR=8)
        float mnew = fmaxf(mrun, mx);
        float fac = __builtin_amdgcn_exp2f(mrun - mnew);
        lrun *= fac;
        f32x4 fv;
#pragma unroll
        for (int r = 0; r < 4; ++r) fv[r] = __shfl(fac, lg * 4 + r);
#pragma unroll
        for (int j = 0; j < 8; ++j) o[j] *= fv;
        mrun = mnew;
      }
      float rs = 0.0f;
#pragma unroll
      for (int nf = 0; nf < 4; ++nf) {
        bf16x4 pk;
#pragma unroll
        for (int r = 0; r < 4; ++r) {
          float p = __builtin_amdgcn_exp2f(sa[nf][r] - mrun);
          rs += p;
          pk[r] = (bf16)p;
        }
        int slot = (nf * 2 + (lg >> 1)) ^ (l15 & 7);
        *(bf16x4*)(Pb + l15 * 128 + slot * 16 + (lg & 1) * 8) = pk;
      }
      rs += __shfl_xor(rs, 16);
      rs += __shfl_xor(rs, 32);
      lrun += rs;
    };
    sfm(saB, mB, lB, oB, qB0, Pw + 2048);
    if (actA) sfm(saA, mA, lA, oA, qA0, Pw);

    // O += P V
#pragma unroll
    for (int ks = 0; ks < 2; ++ks) {
      int slotp = (ks * 4 + lg) ^ (l15 & 7);
      bf16x8 paB = *(const bf16x8*)(Pw + 2048 + l15 * 128 + slotp * 16);
      bf16x8 paA;
      if (actA) paA = *(const bf16x8*)(Pw + l15 * 128 + slotp * 16);
#pragma unroll
      for (int nf2 = 0; nf2 < 8; ++nf2) {
        int d = nf2 * 16 + l15;
        int slot = (ks * 4 + lg) ^ (d & 7);
        bf16x8 vb = *(const bf16x8*)(Vt + d * 128 + slot * 16);
        oB[nf2] = MFMA_BF16(paB, vb, oB[nf2]);
        if (actA) oA[nf2] = MFMA_BF16(paA, vb, oA[nf2]);
      }
    }
    __syncthreads();
  }

  auto epi = [&](f32x4* o, float lrun, int q0) {
    f32x4 linv;
#pragma unroll
    for (int r = 0; r < 4; ++r) linv[r] = 1.0f / __shfl(lrun, lg * 4 + r);
#pragma unroll
    for (int j = 0; j < 8; ++j)
#pragma unroll
      for (int r = 0; r < 4; ++r) {
        size_t row = (size_t)(b * 2048 + q0 + lg * 4 + r);
        AO[row * 2048 + h * 128 + j * 16 + l15] = (bf16)(o[j][r] * linv[r]);
      }
  };
  epi(oB, lB, qB0);
  epi(oA, lA, qA0);
}

// ------------------------------------------------------------------
extern "C" void kernel_launch(void* const* d_in, const int* in_sizes, int n_in,
                              void* d_out, int out_size, void* d_ws, size_t ws_size,
                              hipStream_t stream) {
  const float* hs   = (const float*)d_in[0];
  const float* cosb = (const float*)d_in[1];
  const float* sinb = (const float*)d_in[2];
  const float* Wq   = (const float*)d_in[3];
  const float* Wk   = (const float*)d_in[4];
  const float* Wv   = (const float*)d_in[5];
  const float* Wo   = (const float*)d_in[6];
  float* Out = (float*)d_out;

  char* ws = (char*)d_ws;
  size_t off = 0;
  auto alloc = [&](size_t bytes) { char* p = ws + off; off += bytes; return p; };
  bf16* Xbf = (bf16*)alloc((size_t)4096 * 2048 * 2);
  bf16* Wtq = (bf16*)alloc((size_t)2048 * 2048 * 2);
  bf16* Wtk = (bf16*)alloc((size_t)512 * 2048 * 2);
  bf16* Wtv = (bf16*)alloc((size_t)512 * 2048 * 2);
  bf16* Wto = (bf16*)alloc((size_t)2048 * 2048 * 2);
  bf16* Qb  = (bf16*)alloc((size_t)4096 * 2048 * 2);
  bf16* Kb  = (bf16*)alloc((size_t)4096 * 512 * 2);
  bf16* Vb  = (bf16*)alloc((size_t)4096 * 512 * 2);
  bf16* Vtb = (bf16*)alloc((size_t)4096 * 512 * 2);
  bf16* AO  = (bf16*)alloc((size_t)4096 * 2048 * 2);

  const float SCLQ = 0.08838834764831845f * 1.4426950408889634f;

  dim3 tb(32, 8);
  k_cvt_bf16<<<8192, 256, 0, stream>>>(hs, Xbf, 2097152);
  k_transpose_w<<<dim3(64, 64), tb, 0, stream>>>(Wq, Wtq, 2048, 2048);
  k_transpose_w<<<dim3(64, 16), tb, 0, stream>>>(Wk, Wtk, 2048, 512);
  k_transpose_w<<<dim3(64, 16), tb, 0, stream>>>(Wv, Wtv, 2048, 512);
  k_transpose_w<<<dim3(64, 64), tb, 0, stream>>>(Wo, Wto, 2048, 2048);
  k_gemm_qkv<<<dim3(32, 24), 256, 0, stream>>>(Xbf, Wtq, Wtk, Wtv, Qb, Kb, Vb);
  k_rope<<<16384, 256, 0, stream>>>(Qb, cosb, sinb, 2048, SCLQ);
  k_rope<<<4096, 256, 0, stream>>>(Kb, cosb, sinb, 512, 1.0f);
  k_transpose_v<<<dim3(64, 16, 2), tb, 0, stream>>>(Vb, Vtb);
  k_fattn<<<dim3(16, 16, 2), 256, 0, stream>>>(Qb, Kb, Vtb, AO);
  k_gemm_o<<<dim3(32, 16), 256, 0, stream>>>(AO, Wto, Out);
}

// Round 4
// 315.532 us; speedup vs baseline: 2.7913x; 2.7913x over previous
//
#include <hip/hip_runtime.h>
#include <hip/hip_bf16.h>

// Attention layer: B=2, S=2048, H=2048, NH=16, NKV=4, HD=128, N_REP=4
// cvt X->bf16; transpose weights; fused QKV GEMM (glds+dbuf); RoPE (scale*log2e
// folded into Q); V transpose; balanced strip-pair causal flash attention with
// swapped QK^T + in-lane softmax; O-proj GEMM (f32 out).

typedef __bf16 bf16;
typedef __bf16 bf16x8 __attribute__((ext_vector_type(8)));
typedef __bf16 bf16x4 __attribute__((ext_vector_type(4)));
typedef float  f32x4  __attribute__((ext_vector_type(4)));

#define MFMA_BF16(a, b, c) __builtin_amdgcn_mfma_f32_16x16x32_bf16((a), (b), (c), 0, 0, 0)

__device__ __forceinline__ void glds16(const bf16* g, char* l) {
  __builtin_amdgcn_global_load_lds((__attribute__((address_space(1))) const void*)g,
                                   (__attribute__((address_space(3))) void*)l, 16, 0, 0);
}

// ------------------------------------------------------------------
__global__ __launch_bounds__(256) void k_cvt_bf16(const float* __restrict__ in,
                                                  bf16* __restrict__ out, int n4) {
  int i = blockIdx.x * 256 + threadIdx.x;
  if (i < n4) {
    float4 v = ((const float4*)in)[i];
    bf16x4 o;
    o[0] = (bf16)v.x; o[1] = (bf16)v.y; o[2] = (bf16)v.z; o[3] = (bf16)v.w;
    ((bf16x4*)out)[i] = o;
  }
}

// ------------------------------------------------------------------
// W [Kd][N] f32  ->  Wt [N][Kd] bf16
__global__ __launch_bounds__(256) void k_transpose_w(const float* __restrict__ W,
                                                     bf16* __restrict__ Wt, int Kd, int N) {
  __shared__ float tile[32][33];
  int tx = threadIdx.x, ty = threadIdx.y;
  int kb = blockIdx.x * 32, nb = blockIdx.y * 32;
#pragma unroll
  for (int i = 0; i < 4; ++i)
    tile[ty + i * 8][tx] = W[(size_t)(kb + ty + i * 8) * N + nb + tx];
  __syncthreads();
#pragma unroll
  for (int i = 0; i < 4; ++i)
    Wt[(size_t)(nb + ty + i * 8) * Kd + kb + tx] = (bf16)tile[tx][ty + i * 8];
}

// ------------------------------------------------------------------
// V [4096][512] bf16 -> Vt [(b*4+kv)*128 + d][2048] bf16
__global__ __launch_bounds__(256) void k_transpose_v(const bf16* __restrict__ V,
                                                     bf16* __restrict__ Vt) {
  __shared__ bf16 tile[32][33];
  int tx = threadIdx.x, ty = threadIdx.y;
  int b = blockIdx.z;
  int sb = blockIdx.x * 32, cb = blockIdx.y * 32;
#pragma unroll
  for (int i = 0; i < 4; ++i)
    tile[ty + i * 8][tx] = V[(size_t)(b * 2048 + sb + ty + i * 8) * 512 + cb + tx];
  __syncthreads();
#pragma unroll
  for (int i = 0; i < 4; ++i)
    Vt[(size_t)(b * 512 + cb + ty + i * 8) * 2048 + sb + tx] = tile[tx][ty + i * 8];
}

// ------------------------------------------------------------------
// RoPE in-place; scl folds softmax scale*log2e into Q (1.0 for K).
__global__ __launch_bounds__(256) void k_rope(bf16* __restrict__ T,
                                              const float* __restrict__ cosb,
                                              const float* __restrict__ sinb,
                                              int ncols, float scl) {
  int i = blockIdx.x * 256 + threadIdx.x;
  int npr = ncols >> 1;
  int row = i / npr;
  int p = i - row * npr;
  int h = p >> 6, d = p & 63;
  int c0 = h * 128 + d;
  size_t base = (size_t)row * ncols;
  int s = row & 2047;
  float q0 = (float)T[base + c0];
  float q1 = (float)T[base + c0 + 64];
  float vc0 = cosb[s * 128 + d],      vc1 = cosb[s * 128 + d + 64];
  float vs0 = sinb[s * 128 + d],      vs1 = sinb[s * 128 + d + 64];
  T[base + c0]      = (bf16)((q0 * vc0 - q1 * vs0) * scl);
  T[base + c0 + 64] = (bf16)((q1 * vc1 + q0 * vs1) * scl);
}

// ------------------------------------------------------------------
// GEMM 128x128 tile, BK=64, global_load_lds staging (inverse-swizzled source),
// double-buffered LDS, one barrier per K-step.
template <typename OUT>
__device__ void gemm_block(const bf16* __restrict__ A, const bf16* __restrict__ Bt,
                           OUT* __restrict__ C, int K, int ldc,
                           int rbase, int cbase, char* sm) {
  const int tid = threadIdx.x;
  const int lane = tid & 63, wid = tid >> 6;
  const int l15 = lane & 15, lg = lane >> 4;
  char* Asm = sm;            // 2 x 16KB : [128][128B] swizzled
  char* Bsm = sm + 32768;    // 2 x 16KB

  f32x4 acc[2][8];
#pragma unroll
  for (int i = 0; i < 2; ++i)
#pragma unroll
    for (int j = 0; j < 8; ++j)
#pragma unroll
      for (int r = 0; r < 4; ++r) acc[i][j][r] = 0.0f;

  const int ob = wid * 4096 + lane * 16;
  auto stage = [&](int buf, int kb) {
#pragma unroll
    for (int c = 0; c < 4; ++c) {
      int o = ob + c * 1024;
      int r = o >> 7;
      int cc = ((o >> 4) & 7) ^ (r & 7);
      int dst = wid * 4096 + c * 1024 + buf * 16384;   // wave-uniform LDS base
      glds16(A + (size_t)(rbase + r) * K + kb + cc * 8, Asm + dst);
      glds16(Bt + (size_t)(cbase + r) * K + kb + cc * 8, Bsm + dst);
    }
  };

  stage(0, 0);
  __syncthreads();
  const int nk = K >> 6;
  for (int t = 0; t < nk; ++t) {
    if (t + 1 < nk) stage((t + 1) & 1, (t + 1) << 6);
    const char* At  = Asm + (t & 1) * 16384;
    const char* Bti = Bsm + (t & 1) * 16384;
#pragma unroll
    for (int ks = 0; ks < 2; ++ks) {
      bf16x8 a[2], b[8];
#pragma unroll
      for (int rf = 0; rf < 2; ++rf) {
        int r = wid * 32 + rf * 16 + l15;
        int slot = (ks * 4 + lg) ^ (r & 7);
        a[rf] = *(const bf16x8*)(At + r * 128 + slot * 16);
      }
#pragma unroll
      for (int nf = 0; nf < 8; ++nf) {
        int n = nf * 16 + l15;
        int slot = (ks * 4 + lg) ^ (n & 7);
        b[nf] = *(const bf16x8*)(Bti + n * 128 + slot * 16);
      }
#pragma unroll
      for (int rf = 0; rf < 2; ++rf)
#pragma unroll
        for (int nf = 0; nf < 8; ++nf)
          acc[rf][nf] = MFMA_BF16(a[rf], b[nf], acc[rf][nf]);
    }
    __syncthreads();
  }

#pragma unroll
  for (int rf = 0; rf < 2; ++rf)
#pragma unroll
    for (int nf = 0; nf < 8; ++nf)
#pragma unroll
      for (int r = 0; r < 4; ++r) {
        int row = rbase + wid * 32 + rf * 16 + lg * 4 + r;
        int col = cbase + nf * 16 + l15;
        C[(size_t)row * ldc + col] = (OUT)acc[rf][nf][r];
      }
}

__global__ __launch_bounds__(256, 2) void k_gemm_qkv(const bf16* __restrict__ X,
                                                     const bf16* __restrict__ Wtq,
                                                     const bf16* __restrict__ Wtk,
                                                     const bf16* __restrict__ Wtv,
                                                     bf16* __restrict__ Q,
                                                     bf16* __restrict__ Ko,
                                                     bf16* __restrict__ Vo) {
  __shared__ alignas(16) char sm[65536];
  int nb = blockIdx.y;
  int rbase = blockIdx.x * 128;
  const bf16* Bt; bf16* C; int ldc, cbase;
  if (nb < 16)      { Bt = Wtq; C = Q;  ldc = 2048; cbase = nb * 128; }
  else if (nb < 20) { Bt = Wtk; C = Ko; ldc = 512;  cbase = (nb - 16) * 128; }
  else              { Bt = Wtv; C = Vo; ldc = 512;  cbase = (nb - 20) * 128; }
  gemm_block<bf16>(X, Bt, C, 2048, ldc, rbase, cbase, sm);
}

__global__ __launch_bounds__(256, 2) void k_gemm_o(const bf16* __restrict__ AO,
                                                   const bf16* __restrict__ Wto,
                                                   float* __restrict__ Out) {
  __shared__ alignas(16) char sm[65536];
  gemm_block<float>(AO, Wto, Out, 2048, 2048, blockIdx.x * 128, blockIdx.y * 128, sm);
}

// ------------------------------------------------------------------
// Balanced causal flash attention. 1-D grid of 512; wgid&7 selects (b,kv) so
// all blocks sharing a K/V working set land on one XCD (round-robin mapping).
// Block = strip pair (iA, 31-iA) of 64 q-rows; swapped QK^T + in-lane softmax;
// K/V double-buffered via global_load_lds; 1 barrier/tile.
// __launch_bounds__(256,1): allow up to 512 VGPRs — anti-spill (R3 post-mortem:
// 128-VGPR allocation spilled ~GBs of scratch; LDS already caps at 2 blk/CU).
__global__ __launch_bounds__(256, 1) void k_fattn(const bf16* __restrict__ Qg,
                                                  const bf16* __restrict__ Kg,
                                                  const bf16* __restrict__ Vtg,
                                                  bf16* __restrict__ AO) {
  __shared__ alignas(16) char sm[81920];
  // [0,32768): K 2x(64x256B) ; [32768,65536): Vt 2x(128x128B) ; [65536,81920): P 4x4KB
  const int lane = threadIdx.x & 63, wid = threadIdx.x >> 6;
  const int l15 = lane & 15, lg = lane >> 4;
  const int wg = blockIdx.x;
  const int grp = wg & 7;            // XCD-resident kv-group
  const int b = grp >> 2, kv = grp & 3;
  const int inner = wg >> 3;         // 0..63
  const int iA = inner & 15;
  const int h = kv * 4 + (inner >> 4);
  const int iB = 31 - iA;
  const int qA0 = iA * 64 + wid * 16, qB0 = iB * 64 + wid * 16;
  const int kendA = iA * 64 + 64;
  const int nt = iB + 1;
  char* Pw = sm + 65536 + wid * 4096;   // strip A at +0 (2KB), strip B at +2048

  bf16x8 qfA[4], qfB[4];
#pragma unroll
  for (int kf = 0; kf < 4; ++kf) {
    qfA[kf] = *(const bf16x8*)(Qg + (size_t)(b * 2048 + qA0 + l15) * 2048 + h * 128 + kf * 32 + lg * 8);
    qfB[kf] = *(const bf16x8*)(Qg + (size_t)(b * 2048 + qB0 + l15) * 2048 + h * 128 + kf * 32 + lg * 8);
  }

  f32x4 oA[8], oB[8];
#pragma unroll
  for (int j = 0; j < 8; ++j)
#pragma unroll
    for (int r = 0; r < 4; ++r) { oA[j][r] = 0.0f; oB[j][r] = 0.0f; }
  float mA = -3e38f, lA = 0.0f, mB = -3e38f, lB = 0.0f;

  const int ob = wid * 4096 + lane * 16;
  auto stageKV = [&](int buf, int kb) {
#pragma unroll
    for (int c = 0; c < 4; ++c) {
      int o = ob + c * 1024;
      {
        int r = o >> 8;                      // 0..63
        int slot = (o >> 4) & 15;
        int cc = slot ^ (r & 7);
        glds16(Kg + (size_t)(b * 2048 + kb + r) * 512 + kv * 128 + cc * 8,
               sm + buf * 16384 + wid * 4096 + c * 1024);
      }
      {
        int r = o >> 7;                      // 0..127
        int slot = (o >> 4) & 7;
        int cc = slot ^ (r & 7);
        glds16(Vtg + (size_t)((b * 4 + kv) * 128 + r) * 2048 + kb + cc * 8,
               sm + 32768 + buf * 16384 + wid * 4096 + c * 1024);
      }
    }
  };

  stageKV(0, 0);
  __syncthreads();

  for (int t = 0; t < nt; ++t) {
    const int kb = t << 6;
    if (t + 1 < nt) stageKV((t + 1) & 1, kb + 64);
    const char* Kt = sm + (t & 1) * 16384;
    const char* Vt = sm + 32768 + (t & 1) * 16384;
    const bool actA = kb < kendA;

    f32x4 saA[4], saB[4];
#pragma unroll
    for (int j = 0; j < 4; ++j)
#pragma unroll
      for (int r = 0; r < 4; ++r) { saA[j][r] = 0.0f; saB[j][r] = 0.0f; }

#pragma unroll
    for (int ks = 0; ks < 4; ++ks) {
      bf16x8 bk[4];
#pragma unroll
      for (int nf = 0; nf < 4; ++nf) {
        int n = nf * 16 + l15;
        int slot = (ks * 4 + lg) ^ (n & 7);
        bk[nf] = *(const bf16x8*)(Kt + n * 256 + slot * 16);
      }
#pragma unroll
      for (int nf = 0; nf < 4; ++nf)
        saB[nf] = MFMA_BF16(bk[nf], qfB[ks], saB[nf]);
      if (actA) {
#pragma unroll
        for (int nf = 0; nf < 4; ++nf)
          saA[nf] = MFMA_BF16(bk[nf], qfA[ks], saA[nf]);
      }
    }

    // softmax (values already in log2 units): lane owns one q-row (qi=q0+l15)
    auto sfm = [&](f32x4* sa, float& mrun, float& lrun, f32x4* o, int q0, char* Pb) {
      if (kb + 63 > q0) {
        const int qi = q0 + l15;
#pragma unroll
        for (int nf = 0; nf < 4; ++nf)
#pragma unroll
          for (int r = 0; r < 4; ++r)
            if (kb + nf * 16 + lg * 4 + r > qi) sa[nf][r] = -3e38f;
      }
      float mx = sa[0][0];
#pragma unroll
      for (int nf = 0; nf < 4; ++nf)
#pragma unroll
        for (int r = 0; r < 4; ++r) mx = fmaxf(mx, sa[nf][r]);
      mx = fmaxf(mx, __shfl_xor(mx, 16));
      mx = fmaxf(mx, __shfl_xor(mx, 32));
      if (!__all(mx - mrun <= 8.0f)) {       // defer-max (THR=8)
        float mnew = fmaxf(mrun, mx);
        float fac = __builtin_amdgcn_exp2f(mrun - mnew);
        lrun *= fac;
        f32x4 fv;
#pragma unroll
        for (int r = 0; r < 4; ++r) fv[r] = __shfl(fac, lg * 4 + r);
#pragma unroll
        for (int j = 0; j < 8; ++j) o[j] *= fv;
        mrun = mnew;
      }
      float rs = 0.0f;
#pragma unroll
      for (int nf = 0; nf < 4; ++nf) {
        bf16x4 pk;
#pragma unroll
        for (int r = 0; r < 4; ++r) {
          float p = __builtin_amdgcn_exp2f(sa[nf][r] - mrun);
          rs += p;
          pk[r] = (bf16)p;
        }
        int slot = (nf * 2 + (lg >> 1)) ^ (l15 & 7);
        *(bf16x4*)(Pb + l15 * 128 + slot * 16 + (lg & 1) * 8) = pk;
      }
      rs += __shfl_xor(rs, 16);
      rs += __shfl_xor(rs, 32);
      lrun += rs;
    };
    sfm(saB, mB, lB, oB, qB0, Pw + 2048);
    if (actA) sfm(saA, mA, lA, oA, qA0, Pw);

    // O += P V
#pragma unroll
    for (int ks = 0; ks < 2; ++ks) {
      int slotp = (ks * 4 + lg) ^ (l15 & 7);
      bf16x8 paB = *(const bf16x8*)(Pw + 2048 + l15 * 128 + slotp * 16);
      bf16x8 paA;
      if (actA) paA = *(const bf16x8*)(Pw + l15 * 128 + slotp * 16);
#pragma unroll
      for (int nf2 = 0; nf2 < 8; ++nf2) {
        int d = nf2 * 16 + l15;
        int slot = (ks * 4 + lg) ^ (d & 7);
        bf16x8 vb = *(const bf16x8*)(Vt + d * 128 + slot * 16);
        oB[nf2] = MFMA_BF16(paB, vb, oB[nf2]);
        if (actA) oA[nf2] = MFMA_BF16(paA, vb, oA[nf2]);
      }
    }
    __syncthreads();
  }

  auto epi = [&](f32x4* o, float lrun, int q0) {
    f32x4 linv;
#pragma unroll
    for (int r = 0; r < 4; ++r) linv[r] = 1.0f / __shfl(lrun, lg * 4 + r);
#pragma unroll
    for (int j = 0; j < 8; ++j)
#pragma unroll
      for (int r = 0; r < 4; ++r) {
        size_t row = (size_t)(b * 2048 + q0 + lg * 4 + r);
        AO[row * 2048 + h * 128 + j * 16 + l15] = (bf16)(o[j][r] * linv[r]);
      }
  };
  epi(oB, lB, qB0);
  epi(oA, lA, qA0);
}

// ------------------------------------------------------------------
extern "C" void kernel_launch(void* const* d_in, const int* in_sizes, int n_in,
                              void* d_out, int out_size, void* d_ws, size_t ws_size,
                              hipStream_t stream) {
  const float* hs   = (const float*)d_in[0];
  const float* cosb = (const float*)d_in[1];
  const float* sinb = (const float*)d_in[2];
  const float* Wq   = (const float*)d_in[3];
  const float* Wk   = (const float*)d_in[4];
  const float* Wv   = (const float*)d_in[5];
  const float* Wo   = (const float*)d_in[6];
  float* Out = (float*)d_out;

  char* ws = (char*)d_ws;
  size_t off = 0;
  auto alloc = [&](size_t bytes) { char* p = ws + off; off += bytes; return p; };
  bf16* Xbf = (bf16*)alloc((size_t)4096 * 2048 * 2);
  bf16* Wtq = (bf16*)alloc((size_t)2048 * 2048 * 2);
  bf16* Wtk = (bf16*)alloc((size_t)512 * 2048 * 2);
  bf16* Wtv = (bf16*)alloc((size_t)512 * 2048 * 2);
  bf16* Wto = (bf16*)alloc((size_t)2048 * 2048 * 2);
  bf16* Qb  = (bf16*)alloc((size_t)4096 * 2048 * 2);
  bf16* Kb  = (bf16*)alloc((size_t)4096 * 512 * 2);
  bf16* Vb  = (bf16*)alloc((size_t)4096 * 512 * 2);
  bf16* Vtb = (bf16*)alloc((size_t)4096 * 512 * 2);
  bf16* AO  = (bf16*)alloc((size_t)4096 * 2048 * 2);

  const float SCLQ = 0.08838834764831845f * 1.4426950408889634f;

  dim3 tb(32, 8);
  k_cvt_bf16<<<8192, 256, 0, stream>>>(hs, Xbf, 2097152);
  k_transpose_w<<<dim3(64, 64), tb, 0, stream>>>(Wq, Wtq, 2048, 2048);
  k_transpose_w<<<dim3(64, 16), tb, 0, stream>>>(Wk, Wtk, 2048, 512);
  k_transpose_w<<<dim3(64, 16), tb, 0, stream>>>(Wv, Wtv, 2048, 512);
  k_transpose_w<<<dim3(64, 64), tb, 0, stream>>>(Wo, Wto, 2048, 2048);
  k_gemm_qkv<<<dim3(32, 24), 256, 0, stream>>>(Xbf, Wtq, Wtk, Wtv, Qb, Kb, Vb);
  k_rope<<<16384, 256, 0, stream>>>(Qb, cosb, sinb, 2048, SCLQ);
  k_rope<<<4096, 256, 0, stream>>>(Kb, cosb, sinb, 512, 1.0f);
  k_transpose_v<<<dim3(64, 16, 2), tb, 0, stream>>>(Vb, Vtb);
  k_fattn<<<512, 256, 0, stream>>>(Qb, Kb, Vtb, AO);
  k_gemm_o<<<dim3(32, 16), 256, 0, stream>>>(AO, Wto, Out);
}

// Round 5
// 209.177 us; speedup vs baseline: 4.2106x; 1.5084x over previous
//
#include <hip/hip_runtime.h>
#include <hip/hip_bf16.h>

// Attention layer: B=2, S=2048, H=2048, NH=16, NKV=4, HD=128, N_REP=4
// cvt X->bf16; transpose weights; fused QKV GEMM (glds+dbuf); RoPE (scale*log2e
// folded into Q); V transpose; single-strip causal flash attention (KVBLK=32,
// dbuf, 4 blocks/CU) with swapped QK^T + in-lane softmax; O-proj GEMM (f32 out).

typedef __bf16 bf16;
typedef __bf16 bf16x8 __attribute__((ext_vector_type(8)));
typedef __bf16 bf16x4 __attribute__((ext_vector_type(4)));
typedef float  f32x4  __attribute__((ext_vector_type(4)));

#define MFMA_BF16(a, b, c) __builtin_amdgcn_mfma_f32_16x16x32_bf16((a), (b), (c), 0, 0, 0)

__device__ __forceinline__ void glds16(const bf16* g, char* l) {
  __builtin_amdgcn_global_load_lds((__attribute__((address_space(1))) const void*)g,
                                   (__attribute__((address_space(3))) void*)l, 16, 0, 0);
}

// ------------------------------------------------------------------
__global__ __launch_bounds__(256) void k_cvt_bf16(const float* __restrict__ in,
                                                  bf16* __restrict__ out, int n4) {
  int i = blockIdx.x * 256 + threadIdx.x;
  if (i < n4) {
    float4 v = ((const float4*)in)[i];
    bf16x4 o;
    o[0] = (bf16)v.x; o[1] = (bf16)v.y; o[2] = (bf16)v.z; o[3] = (bf16)v.w;
    ((bf16x4*)out)[i] = o;
  }
}

// ------------------------------------------------------------------
// W [Kd][N] f32  ->  Wt [N][Kd] bf16
__global__ __launch_bounds__(256) void k_transpose_w(const float* __restrict__ W,
                                                     bf16* __restrict__ Wt, int Kd, int N) {
  __shared__ float tile[32][33];
  int tx = threadIdx.x, ty = threadIdx.y;
  int kb = blockIdx.x * 32, nb = blockIdx.y * 32;
#pragma unroll
  for (int i = 0; i < 4; ++i)
    tile[ty + i * 8][tx] = W[(size_t)(kb + ty + i * 8) * N + nb + tx];
  __syncthreads();
#pragma unroll
  for (int i = 0; i < 4; ++i)
    Wt[(size_t)(nb + ty + i * 8) * Kd + kb + tx] = (bf16)tile[tx][ty + i * 8];
}

// ------------------------------------------------------------------
// V [4096][512] bf16 -> Vt [(b*4+kv)*128 + d][2048] bf16
__global__ __launch_bounds__(256) void k_transpose_v(const bf16* __restrict__ V,
                                                     bf16* __restrict__ Vt) {
  __shared__ bf16 tile[32][33];
  int tx = threadIdx.x, ty = threadIdx.y;
  int b = blockIdx.z;
  int sb = blockIdx.x * 32, cb = blockIdx.y * 32;
#pragma unroll
  for (int i = 0; i < 4; ++i)
    tile[ty + i * 8][tx] = V[(size_t)(b * 2048 + sb + ty + i * 8) * 512 + cb + tx];
  __syncthreads();
#pragma unroll
  for (int i = 0; i < 4; ++i)
    Vt[(size_t)(b * 512 + cb + ty + i * 8) * 2048 + sb + tx] = tile[tx][ty + i * 8];
}

// ------------------------------------------------------------------
// RoPE in-place; scl folds softmax scale*log2e into Q (1.0 for K).
__global__ __launch_bounds__(256) void k_rope(bf16* __restrict__ T,
                                              const float* __restrict__ cosb,
                                              const float* __restrict__ sinb,
                                              int ncols, float scl) {
  int i = blockIdx.x * 256 + threadIdx.x;
  int npr = ncols >> 1;
  int row = i / npr;
  int p = i - row * npr;
  int h = p >> 6, d = p & 63;
  int c0 = h * 128 + d;
  size_t base = (size_t)row * ncols;
  int s = row & 2047;
  float q0 = (float)T[base + c0];
  float q1 = (float)T[base + c0 + 64];
  float vc0 = cosb[s * 128 + d],      vc1 = cosb[s * 128 + d + 64];
  float vs0 = sinb[s * 128 + d],      vs1 = sinb[s * 128 + d + 64];
  T[base + c0]      = (bf16)((q0 * vc0 - q1 * vs0) * scl);
  T[base + c0 + 64] = (bf16)((q1 * vc1 + q0 * vs1) * scl);
}

// ------------------------------------------------------------------
// GEMM 128x128 tile, BK=64, global_load_lds staging (inverse-swizzled source),
// double-buffered LDS, one barrier per K-step.
template <typename OUT>
__device__ void gemm_block(const bf16* __restrict__ A, const bf16* __restrict__ Bt,
                           OUT* __restrict__ C, int K, int ldc,
                           int rbase, int cbase, char* sm) {
  const int tid = threadIdx.x;
  const int lane = tid & 63, wid = tid >> 6;
  const int l15 = lane & 15, lg = lane >> 4;
  char* Asm = sm;            // 2 x 16KB : [128][128B] swizzled
  char* Bsm = sm + 32768;    // 2 x 16KB

  f32x4 acc[2][8];
#pragma unroll
  for (int i = 0; i < 2; ++i)
#pragma unroll
    for (int j = 0; j < 8; ++j)
#pragma unroll
      for (int r = 0; r < 4; ++r) acc[i][j][r] = 0.0f;

  const int ob = wid * 4096 + lane * 16;
  auto stage = [&](int buf, int kb) {
#pragma unroll
    for (int c = 0; c < 4; ++c) {
      int o = ob + c * 1024;
      int r = o >> 7;
      int cc = ((o >> 4) & 7) ^ (r & 7);
      int dst = wid * 4096 + c * 1024 + buf * 16384;   // wave-uniform LDS base
      glds16(A + (size_t)(rbase + r) * K + kb + cc * 8, Asm + dst);
      glds16(Bt + (size_t)(cbase + r) * K + kb + cc * 8, Bsm + dst);
    }
  };

  stage(0, 0);
  __syncthreads();
  const int nk = K >> 6;
  for (int t = 0; t < nk; ++t) {
    if (t + 1 < nk) stage((t + 1) & 1, (t + 1) << 6);
    const char* At  = Asm + (t & 1) * 16384;
    const char* Bti = Bsm + (t & 1) * 16384;
#pragma unroll
    for (int ks = 0; ks < 2; ++ks) {
      bf16x8 a[2], b[8];
#pragma unroll
      for (int rf = 0; rf < 2; ++rf) {
        int r = wid * 32 + rf * 16 + l15;
        int slot = (ks * 4 + lg) ^ (r & 7);
        a[rf] = *(const bf16x8*)(At + r * 128 + slot * 16);
      }
#pragma unroll
      for (int nf = 0; nf < 8; ++nf) {
        int n = nf * 16 + l15;
        int slot = (ks * 4 + lg) ^ (n & 7);
        b[nf] = *(const bf16x8*)(Bti + n * 128 + slot * 16);
      }
#pragma unroll
      for (int rf = 0; rf < 2; ++rf)
#pragma unroll
        for (int nf = 0; nf < 8; ++nf)
          acc[rf][nf] = MFMA_BF16(a[rf], b[nf], acc[rf][nf]);
    }
    __syncthreads();
  }

#pragma unroll
  for (int rf = 0; rf < 2; ++rf)
#pragma unroll
    for (int nf = 0; nf < 8; ++nf)
#pragma unroll
      for (int r = 0; r < 4; ++r) {
        int row = rbase + wid * 32 + rf * 16 + lg * 4 + r;
        int col = cbase + nf * 16 + l15;
        C[(size_t)row * ldc + col] = (OUT)acc[rf][nf][r];
      }
}

__global__ __launch_bounds__(256, 2) void k_gemm_qkv(const bf16* __restrict__ X,
                                                     const bf16* __restrict__ Wtq,
                                                     const bf16* __restrict__ Wtk,
                                                     const bf16* __restrict__ Wtv,
                                                     bf16* __restrict__ Q,
                                                     bf16* __restrict__ Ko,
                                                     bf16* __restrict__ Vo) {
  __shared__ alignas(16) char sm[65536];
  int nb = blockIdx.y;
  int rbase = blockIdx.x * 128;
  const bf16* Bt; bf16* C; int ldc, cbase;
  if (nb < 16)      { Bt = Wtq; C = Q;  ldc = 2048; cbase = nb * 128; }
  else if (nb < 20) { Bt = Wtk; C = Ko; ldc = 512;  cbase = (nb - 16) * 128; }
  else              { Bt = Wtv; C = Vo; ldc = 512;  cbase = (nb - 20) * 128; }
  gemm_block<bf16>(X, Bt, C, 2048, ldc, rbase, cbase, sm);
}

__global__ __launch_bounds__(256, 2) void k_gemm_o(const bf16* __restrict__ AO,
                                                   const bf16* __restrict__ Wto,
                                                   float* __restrict__ Out) {
  __shared__ alignas(16) char sm[65536];
  gemm_block<float>(AO, Wto, Out, 2048, 2048, blockIdx.x * 128, blockIdx.y * 128, sm);
}

// ------------------------------------------------------------------
// Single-strip causal flash attention. Block = one strip of 64 q-rows
// (4 waves x 16 rows), KVBLK=32, K/V double-buffered via global_load_lds,
// 1 barrier/tile. LDS 37.9KB -> 4 blocks/CU; launch_bounds(256,4) caps
// VGPR at 128 (R4 post-mortem: 220 VGPR + 80KB LDS = 1 block/CU disaster).
// Grid 1024: wg&7 = (b,kv) XCD group; strips dispatched longest-first.
__global__ __launch_bounds__(256, 4) void k_fattn(const bf16* __restrict__ Qg,
                                                  const bf16* __restrict__ Kg,
                                                  const bf16* __restrict__ Vtg,
                                                  bf16* __restrict__ AO) {
  __shared__ alignas(16) char sm[37888];
  // [0,16384): K 2x(32x256B) ; [16384,32768): Vt 2x(128x64B) ; [32768,37888): P 4x1280B
  const int lane = threadIdx.x & 63, wid = threadIdx.x >> 6;
  const int l15 = lane & 15, lg = lane >> 4;
  const int wg = blockIdx.x;
  const int grp = wg & 7;            // XCD-resident (b,kv) group
  const int b = grp >> 2, kv = grp & 3;
  const int inner = wg >> 3;         // 0..127
  const int h = kv * 4 + (inner & 3);
  const int strip = 31 - (inner >> 2);   // longest-first dispatch
  const int q0 = strip * 64 + wid * 16;
  const int nt = 2 * (strip + 1);
  char* Pw = sm + 32768 + wid * 1280;    // [16 rows][80B] padded

  // Q fragments (B-operand of swapped QK^T): lane l15 = q-row, lg = d-octet
  bf16x8 qf[4];
#pragma unroll
  for (int kf = 0; kf < 4; ++kf)
    qf[kf] = *(const bf16x8*)(Qg + (size_t)(b * 2048 + q0 + l15) * 2048 + h * 128 + kf * 32 + lg * 8);

  f32x4 o[8];
#pragma unroll
  for (int j = 0; j < 8; ++j)
#pragma unroll
    for (int r = 0; r < 4; ++r) o[j][r] = 0.0f;
  float mrun = -3e38f, lrun = 0.0f;

  // stage one KVBLK=32 tile: K 8KB (rows 256B, 16 slots, cc = slot ^ row&15)
  //                          V 8KB (rows 64B, 4 slots, cc = slot ^ (row>>1)&3)
  auto stageKV = [&](int buf, int kb) {
#pragma unroll
    for (int j = 0; j < 2; ++j) {
      int c = wid * 128 + j * 64 + lane;
      int kr = c >> 4, kslot = c & 15;
      int kcc = kslot ^ (kr & 15);
      glds16(Kg + (size_t)(b * 2048 + kb + kr) * 512 + kv * 128 + kcc * 8,
             sm + buf * 8192 + wid * 2048 + j * 1024);
      int vr = c >> 2, vslot = c & 3;
      int vcc = vslot ^ ((vr >> 1) & 3);
      glds16(Vtg + (size_t)((b * 4 + kv) * 128 + vr) * 2048 + kb + vcc * 8,
             sm + 16384 + buf * 8192 + wid * 2048 + j * 1024);
    }
  };

  stageKV(0, 0);
  __syncthreads();

  for (int t = 0; t < nt; ++t) {
    const int kb = t << 5;
    if (t + 1 < nt) stageKV((t + 1) & 1, kb + 32);
    const char* Kt = sm + (t & 1) * 8192;
    const char* Vt = sm + 16384 + (t & 1) * 8192;

    // S^T = K Q^T : rows k = nf*16+lg*4+r, col q = l15
    f32x4 sa[2];
#pragma unroll
    for (int j = 0; j < 2; ++j)
#pragma unroll
      for (int r = 0; r < 4; ++r) sa[j][r] = 0.0f;
#pragma unroll
    for (int kf = 0; kf < 4; ++kf) {
#pragma unroll
      for (int nf = 0; nf < 2; ++nf) {
        int slot = (kf * 4 + lg) ^ l15;
        bf16x8 bk = *(const bf16x8*)(Kt + (nf * 16 + l15) * 256 + slot * 16);
        sa[nf] = MFMA_BF16(bk, qf[kf], sa[nf]);
      }
    }

    // causal mask
    if (kb + 31 > q0) {
      const int qi = q0 + l15;
#pragma unroll
      for (int nf = 0; nf < 2; ++nf)
#pragma unroll
        for (int r = 0; r < 4; ++r)
          if (kb + nf * 16 + lg * 4 + r > qi) sa[nf][r] = -3e38f;
    }

    // in-lane softmax (log2 units); row q=l15 split across 4 lg-lanes
    float mx = sa[0][0];
#pragma unroll
    for (int nf = 0; nf < 2; ++nf)
#pragma unroll
      for (int r = 0; r < 4; ++r) mx = fmaxf(mx, sa[nf][r]);
    mx = fmaxf(mx, __shfl_xor(mx, 16));
    mx = fmaxf(mx, __shfl_xor(mx, 32));
    if (!__all(mx - mrun <= 8.0f)) {       // defer-max (THR=8)
      float mnew = fmaxf(mrun, mx);
      float fac = __builtin_amdgcn_exp2f(mrun - mnew);
      lrun *= fac;
      f32x4 fv;
#pragma unroll
      for (int r = 0; r < 4; ++r) fv[r] = __shfl(fac, lg * 4 + r);
#pragma unroll
      for (int j = 0; j < 8; ++j) o[j] *= fv;
      mrun = mnew;
    }
    float rs = 0.0f;
#pragma unroll
    for (int nf = 0; nf < 2; ++nf) {
      bf16x4 pk;
#pragma unroll
      for (int r = 0; r < 4; ++r) {
        float p = __builtin_amdgcn_exp2f(sa[nf][r] - mrun);
        rs += p;
        pk[r] = (bf16)p;
      }
      *(bf16x4*)(Pw + l15 * 80 + nf * 32 + lg * 8) = pk;   // P[q=l15][k], padded rows
    }
    rs += __shfl_xor(rs, 16);
    rs += __shfl_xor(rs, 32);
    lrun += rs;

    // O += P V : A = P (row q=l15, k-octet lg), B = Vt rows d
    bf16x8 pa = *(const bf16x8*)(Pw + l15 * 80 + lg * 16);
#pragma unroll
    for (int nf2 = 0; nf2 < 8; ++nf2) {
      int d = nf2 * 16 + l15;
      int slot = lg ^ ((d >> 1) & 3);
      bf16x8 vb = *(const bf16x8*)(Vt + d * 64 + slot * 16);
      o[nf2] = MFMA_BF16(pa, vb, o[nf2]);
    }
    __syncthreads();
  }

  // epilogue: O /= l ; O rows q=lg*4+r, col d=nf2*16+l15
  f32x4 linv;
#pragma unroll
  for (int r = 0; r < 4; ++r) linv[r] = 1.0f / __shfl(lrun, lg * 4 + r);
#pragma unroll
  for (int j = 0; j < 8; ++j)
#pragma unroll
    for (int r = 0; r < 4; ++r) {
      size_t row = (size_t)(b * 2048 + q0 + lg * 4 + r);
      AO[row * 2048 + h * 128 + j * 16 + l15] = (bf16)(o[j][r] * linv[r]);
    }
}

// ------------------------------------------------------------------
extern "C" void kernel_launch(void* const* d_in, const int* in_sizes, int n_in,
                              void* d_out, int out_size, void* d_ws, size_t ws_size,
                              hipStream_t stream) {
  const float* hs   = (const float*)d_in[0];
  const float* cosb = (const float*)d_in[1];
  const float* sinb = (const float*)d_in[2];
  const float* Wq   = (const float*)d_in[3];
  const float* Wk   = (const float*)d_in[4];
  const float* Wv   = (const float*)d_in[5];
  const float* Wo   = (const float*)d_in[6];
  float* Out = (float*)d_out;

  char* ws = (char*)d_ws;
  size_t off = 0;
  auto alloc = [&](size_t bytes) { char* p = ws + off; off += bytes; return p; };
  bf16* Xbf = (bf16*)alloc((size_t)4096 * 2048 * 2);
  bf16* Wtq = (bf16*)alloc((size_t)2048 * 2048 * 2);
  bf16* Wtk = (bf16*)alloc((size_t)512 * 2048 * 2);
  bf16* Wtv = (bf16*)alloc((size_t)512 * 2048 * 2);
  bf16* Wto = (bf16*)alloc((size_t)2048 * 2048 * 2);
  bf16* Qb  = (bf16*)alloc((size_t)4096 * 2048 * 2);
  bf16* Kb  = (bf16*)alloc((size_t)4096 * 512 * 2);
  bf16* Vb  = (bf16*)alloc((size_t)4096 * 512 * 2);
  bf16* Vtb = (bf16*)alloc((size_t)4096 * 512 * 2);
  bf16* AO  = (bf16*)alloc((size_t)4096 * 2048 * 2);

  const float SCLQ = 0.08838834764831845f * 1.4426950408889634f;

  dim3 tb(32, 8);
  k_cvt_bf16<<<8192, 256, 0, stream>>>(hs, Xbf, 2097152);
  k_transpose_w<<<dim3(64, 64), tb, 0, stream>>>(Wq, Wtq, 2048, 2048);
  k_transpose_w<<<dim3(64, 16), tb, 0, stream>>>(Wk, Wtk, 2048, 512);
  k_transpose_w<<<dim3(64, 16), tb, 0, stream>>>(Wv, Wtv, 2048, 512);
  k_transpose_w<<<dim3(64, 64), tb, 0, stream>>>(Wo, Wto, 2048, 2048);
  k_gemm_qkv<<<dim3(32, 24), 256, 0, stream>>>(Xbf, Wtq, Wtk, Wtv, Qb, Kb, Vb);
  k_rope<<<16384, 256, 0, stream>>>(Qb, cosb, sinb, 2048, SCLQ);
  k_rope<<<4096, 256, 0, stream>>>(Kb, cosb, sinb, 512, 1.0f);
  k_transpose_v<<<dim3(64, 16, 2), tb, 0, stream>>>(Vb, Vtb);
  k_fattn<<<1024, 256, 0, stream>>>(Qb, Kb, Vtb, AO);
  k_gemm_o<<<dim3(32, 16), 256, 0, stream>>>(AO, Wto, Out);
}

// Round 6
// 202.591 us; speedup vs baseline: 4.3475x; 1.0325x over previous
//
#include <hip/hip_runtime.h>
#include <hip/hip_bf16.h>

// Attention layer: B=2, S=2048, H=2048, NH=16, NKV=4, HD=128, N_REP=4
// cvt X->bf16; merged weight transpose; fused QKV GEMM with RoPE epilogue;
// V transpose; single-strip causal flash attention (KVBLK=32, dbuf glds,
// 4 blocks/CU, interleaved dispatch); O-proj GEMM (f32 out).

typedef __bf16 bf16;
typedef __bf16 bf16x8 __attribute__((ext_vector_type(8)));
typedef __bf16 bf16x4 __attribute__((ext_vector_type(4)));
typedef float  f32x4  __attribute__((ext_vector_type(4)));

#define MFMA_BF16(a, b, c) __builtin_amdgcn_mfma_f32_16x16x32_bf16((a), (b), (c), 0, 0, 0)

__device__ __forceinline__ void glds16(const bf16* g, char* l) {
  __builtin_amdgcn_global_load_lds((__attribute__((address_space(1))) const void*)g,
                                   (__attribute__((address_space(3))) void*)l, 16, 0, 0);
}

// ------------------------------------------------------------------
__global__ __launch_bounds__(256) void k_cvt_bf16(const float* __restrict__ in,
                                                  bf16* __restrict__ out, int n4) {
  int i = blockIdx.x * 256 + threadIdx.x;
  if (i < n4) {
    float4 v = ((const float4*)in)[i];
    bf16x4 o;
    o[0] = (bf16)v.x; o[1] = (bf16)v.y; o[2] = (bf16)v.z; o[3] = (bf16)v.w;
    ((bf16x4*)out)[i] = o;
  }
}

// ------------------------------------------------------------------
// Merged weight transpose: W [Kd=2048][N] f32 -> Wt [N][2048] bf16.
// z: 0=Wq(N=2048) 1=Wo(N=2048) 2=Wk(N=512) 3=Wv(N=512).
__global__ __launch_bounds__(256) void k_transpose_w4(const float* __restrict__ Wq,
                                                      const float* __restrict__ Wk,
                                                      const float* __restrict__ Wv,
                                                      const float* __restrict__ Wo,
                                                      bf16* __restrict__ Wtq,
                                                      bf16* __restrict__ Wtk,
                                                      bf16* __restrict__ Wtv,
                                                      bf16* __restrict__ Wto) {
  int z = blockIdx.z;
  const float* W; bf16* Wt; int N;
  if (z == 0)      { W = Wq; Wt = Wtq; N = 2048; }
  else if (z == 1) { W = Wo; Wt = Wto; N = 2048; }
  else if (z == 2) { W = Wk; Wt = Wtk; N = 512; }
  else             { W = Wv; Wt = Wtv; N = 512; }
  int nb = blockIdx.y * 32;
  if (nb >= N) return;
  __shared__ float tile[32][33];
  int tx = threadIdx.x, ty = threadIdx.y;
  int kb = blockIdx.x * 32;
#pragma unroll
  for (int i = 0; i < 4; ++i)
    tile[ty + i * 8][tx] = W[(size_t)(kb + ty + i * 8) * N + nb + tx];
  __syncthreads();
#pragma unroll
  for (int i = 0; i < 4; ++i)
    Wt[(size_t)(nb + ty + i * 8) * 2048 + kb + tx] = (bf16)tile[tx][ty + i * 8];
}

// ------------------------------------------------------------------
// V [4096][512] bf16 -> Vt [(b*4+kv)*128 + d][2048] bf16
__global__ __launch_bounds__(256) void k_transpose_v(const bf16* __restrict__ V,
                                                     bf16* __restrict__ Vt) {
  __shared__ bf16 tile[32][33];
  int tx = threadIdx.x, ty = threadIdx.y;
  int b = blockIdx.z;
  int sb = blockIdx.x * 32, cb = blockIdx.y * 32;
#pragma unroll
  for (int i = 0; i < 4; ++i)
    tile[ty + i * 8][tx] = V[(size_t)(b * 2048 + sb + ty + i * 8) * 512 + cb + tx];
  __syncthreads();
#pragma unroll
  for (int i = 0; i < 4; ++i)
    Vt[(size_t)(b * 512 + cb + ty + i * 8) * 2048 + sb + tx] = tile[tx][ty + i * 8];
}

// ------------------------------------------------------------------
// GEMM 128x128 tile, BK=64, global_load_lds staging (inverse-swizzled source),
// double-buffered LDS, one barrier per K-step. Optional fused RoPE epilogue:
// rope_scl != 0 applies q' = q*cos + rot(q)*sin, scaled (cols are one head,
// pairs (d,d+64) = acc[nf], acc[nf+4] in the SAME lane).
template <typename OUT>
__device__ void gemm_block(const bf16* __restrict__ A, const bf16* __restrict__ Bt,
                           OUT* __restrict__ C, int K, int ldc,
                           int rbase, int cbase, char* sm,
                           float rope_scl, const float* __restrict__ cosb,
                           const float* __restrict__ sinb) {
  const int tid = threadIdx.x;
  const int lane = tid & 63, wid = tid >> 6;
  const int l15 = lane & 15, lg = lane >> 4;
  char* Asm = sm;            // 2 x 16KB : [128][128B] swizzled
  char* Bsm = sm + 32768;    // 2 x 16KB

  f32x4 acc[2][8];
#pragma unroll
  for (int i = 0; i < 2; ++i)
#pragma unroll
    for (int j = 0; j < 8; ++j)
#pragma unroll
      for (int r = 0; r < 4; ++r) acc[i][j][r] = 0.0f;

  const int ob = wid * 4096 + lane * 16;
  auto stage = [&](int buf, int kb) {
#pragma unroll
    for (int c = 0; c < 4; ++c) {
      int o = ob + c * 1024;
      int r = o >> 7;
      int cc = ((o >> 4) & 7) ^ (r & 7);
      int dst = wid * 4096 + c * 1024 + buf * 16384;   // wave-uniform LDS base
      glds16(A + (size_t)(rbase + r) * K + kb + cc * 8, Asm + dst);
      glds16(Bt + (size_t)(cbase + r) * K + kb + cc * 8, Bsm + dst);
    }
  };

  stage(0, 0);
  __syncthreads();
  const int nk = K >> 6;
  for (int t = 0; t < nk; ++t) {
    if (t + 1 < nk) stage((t + 1) & 1, (t + 1) << 6);
    const char* At  = Asm + (t & 1) * 16384;
    const char* Bti = Bsm + (t & 1) * 16384;
#pragma unroll
    for (int ks = 0; ks < 2; ++ks) {
      bf16x8 a[2], b[8];
#pragma unroll
      for (int rf = 0; rf < 2; ++rf) {
        int r = wid * 32 + rf * 16 + l15;
        int slot = (ks * 4 + lg) ^ (r & 7);
        a[rf] = *(const bf16x8*)(At + r * 128 + slot * 16);
      }
#pragma unroll
      for (int nf = 0; nf < 8; ++nf) {
        int n = nf * 16 + l15;
        int slot = (ks * 4 + lg) ^ (n & 7);
        b[nf] = *(const bf16x8*)(Bti + n * 128 + slot * 16);
      }
#pragma unroll
      for (int rf = 0; rf < 2; ++rf)
#pragma unroll
        for (int nf = 0; nf < 8; ++nf)
          acc[rf][nf] = MFMA_BF16(a[rf], b[nf], acc[rf][nf]);
    }
    __syncthreads();
  }

  if (rope_scl != 0.0f) {
#pragma unroll
    for (int rf = 0; rf < 2; ++rf)
#pragma unroll
      for (int r = 0; r < 4; ++r) {
        int s = (rbase + wid * 32 + rf * 16 + lg * 4 + r) & 2047;
#pragma unroll
        for (int nf = 0; nf < 4; ++nf) {
          int d = nf * 16 + l15;
          float v0 = acc[rf][nf][r], v1 = acc[rf][nf + 4][r];
          float c0 = cosb[s * 128 + d],      c1 = cosb[s * 128 + d + 64];
          float s0 = sinb[s * 128 + d],      s1 = sinb[s * 128 + d + 64];
          acc[rf][nf][r]     = (v0 * c0 - v1 * s0) * rope_scl;
          acc[rf][nf + 4][r] = (v1 * c1 + v0 * s1) * rope_scl;
        }
      }
  }

#pragma unroll
  for (int rf = 0; rf < 2; ++rf)
#pragma unroll
    for (int nf = 0; nf < 8; ++nf)
#pragma unroll
      for (int r = 0; r < 4; ++r) {
        int row = rbase + wid * 32 + rf * 16 + lg * 4 + r;
        int col = cbase + nf * 16 + l15;
        C[(size_t)row * ldc + col] = (OUT)acc[rf][nf][r];
      }
}

__global__ __launch_bounds__(256, 2) void k_gemm_qkv(const bf16* __restrict__ X,
                                                     const bf16* __restrict__ Wtq,
                                                     const bf16* __restrict__ Wtk,
                                                     const bf16* __restrict__ Wtv,
                                                     bf16* __restrict__ Q,
                                                     bf16* __restrict__ Ko,
                                                     bf16* __restrict__ Vo,
                                                     const float* __restrict__ cosb,
                                                     const float* __restrict__ sinb,
                                                     float sclq) {
  __shared__ alignas(16) char sm[65536];
  int nb = blockIdx.y;
  int rbase = blockIdx.x * 128;
  const bf16* Bt; bf16* C; int ldc, cbase; float rs;
  if (nb < 16)      { Bt = Wtq; C = Q;  ldc = 2048; cbase = nb * 128;        rs = sclq; }
  else if (nb < 20) { Bt = Wtk; C = Ko; ldc = 512;  cbase = (nb - 16) * 128; rs = 1.0f; }
  else              { Bt = Wtv; C = Vo; ldc = 512;  cbase = (nb - 20) * 128; rs = 0.0f; }
  gemm_block<bf16>(X, Bt, C, 2048, ldc, rbase, cbase, sm, rs, cosb, sinb);
}

__global__ __launch_bounds__(256, 2) void k_gemm_o(const bf16* __restrict__ AO,
                                                   const bf16* __restrict__ Wto,
                                                   float* __restrict__ Out) {
  __shared__ alignas(16) char sm[65536];
  gemm_block<float>(AO, Wto, Out, 2048, 2048, blockIdx.x * 128, blockIdx.y * 128, sm,
                    0.0f, nullptr, nullptr);
}

// ------------------------------------------------------------------
// Single-strip causal flash attention. Block = one strip of 64 q-rows
// (4 waves x 16 rows), KVBLK=32, K/V double-buffered via global_load_lds,
// 1 barrier/tile. LDS 37.9KB -> 4 blocks/CU; launch_bounds(256,4) caps VGPR
// at 128. Grid 1024: wg&7 = (b,kv) XCD group; strips dispatched interleaved
// long/short (31,0,30,1,...) so resident blocks per CU mix lengths.
__global__ __launch_bounds__(256, 4) void k_fattn(const bf16* __restrict__ Qg,
                                                  const bf16* __restrict__ Kg,
                                                  const bf16* __restrict__ Vtg,
                                                  bf16* __restrict__ AO) {
  __shared__ alignas(16) char sm[37888];
  // [0,16384): K 2x(32x256B) ; [16384,32768): Vt 2x(128x64B) ; [32768,37888): P 4x1280B
  const int lane = threadIdx.x & 63, wid = threadIdx.x >> 6;
  const int l15 = lane & 15, lg = lane >> 4;
  const int wg = blockIdx.x;
  const int grp = wg & 7;            // XCD-resident (b,kv) group
  const int b = grp >> 2, kv = grp & 3;
  const int inner = wg >> 3;         // 0..127
  const int h = kv * 4 + (inner & 3);
  const int si = inner >> 2;         // 0..31
  const int strip = (si & 1) ? (si >> 1) : (31 - (si >> 1));  // 31,0,30,1,...
  const int q0 = strip * 64 + wid * 16;
  const int nt = 2 * (strip + 1);
  char* Pw = sm + 32768 + wid * 1280;    // [16 rows][80B] padded

  // Q fragments (B-operand of swapped QK^T): lane l15 = q-row, lg = d-octet
  bf16x8 qf[4];
#pragma unroll
  for (int kf = 0; kf < 4; ++kf)
    qf[kf] = *(const bf16x8*)(Qg + (size_t)(b * 2048 + q0 + l15) * 2048 + h * 128 + kf * 32 + lg * 8);

  f32x4 o[8];
#pragma unroll
  for (int j = 0; j < 8; ++j)
#pragma unroll
    for (int r = 0; r < 4; ++r) o[j][r] = 0.0f;
  float mrun = -3e38f, lrun = 0.0f;

  // Per-thread staging source pointers, advanced by constant stride per tile
  // (hoists 64-bit addr recompute out of the loop).
  const bf16* ksrc[2];
  const bf16* vsrc[2];
  int kdst[2], vdst[2];
#pragma unroll
  for (int j = 0; j < 2; ++j) {
    int c = wid * 128 + j * 64 + lane;
    int kr = c >> 4, kslot = c & 15;
    int kcc = kslot ^ (kr & 15);
    ksrc[j] = Kg + (size_t)(b * 2048 + kr) * 512 + kv * 128 + kcc * 8;
    kdst[j] = wid * 2048 + j * 1024;
    int vr = c >> 2, vslot = c & 3;
    int vcc = vslot ^ ((vr >> 1) & 3);
    vsrc[j] = Vtg + (size_t)((b * 4 + kv) * 128 + vr) * 2048 + vcc * 8;
    vdst[j] = 16384 + wid * 2048 + j * 1024;
  }
  auto stageKV = [&](int buf) {
#pragma unroll
    for (int j = 0; j < 2; ++j) {
      glds16(ksrc[j], sm + buf * 8192 + kdst[j]);
      glds16(vsrc[j], sm + buf * 8192 + vdst[j]);
      ksrc[j] += 32 * 512;   // next 32 kv rows
      vsrc[j] += 32;         // next 32 seq cols
    }
  };

  stageKV(0);
  __syncthreads();

  for (int t = 0; t < nt; ++t) {
    const int kb = t << 5;
    if (t + 1 < nt) stageKV((t + 1) & 1);
    const char* Kt = sm + (t & 1) * 8192;
    const char* Vt = sm + 16384 + (t & 1) * 8192;

    // S^T = K Q^T : rows k = nf*16+lg*4+r, col q = l15
    f32x4 sa[2];
#pragma unroll
    for (int j = 0; j < 2; ++j)
#pragma unroll
      for (int r = 0; r < 4; ++r) sa[j][r] = 0.0f;
#pragma unroll
    for (int kf = 0; kf < 4; ++kf) {
#pragma unroll
      for (int nf = 0; nf < 2; ++nf) {
        int slot = (kf * 4 + lg) ^ l15;
        bf16x8 bk = *(const bf16x8*)(Kt + (nf * 16 + l15) * 256 + slot * 16);
        sa[nf] = MFMA_BF16(bk, qf[kf], sa[nf]);
      }
    }

    // causal mask
    if (kb + 31 > q0) {
      const int qi = q0 + l15;
#pragma unroll
      for (int nf = 0; nf < 2; ++nf)
#pragma unroll
        for (int r = 0; r < 4; ++r)
          if (kb + nf * 16 + lg * 4 + r > qi) sa[nf][r] = -3e38f;
    }

    // in-lane softmax (log2 units); row q=l15 split across 4 lg-lanes
    float mx = sa[0][0];
#pragma unroll
    for (int nf = 0; nf < 2; ++nf)
#pragma unroll
      for (int r = 0; r < 4; ++r) mx = fmaxf(mx, sa[nf][r]);
    mx = fmaxf(mx, __shfl_xor(mx, 16));
    mx = fmaxf(mx, __shfl_xor(mx, 32));
    if (!__all(mx - mrun <= 8.0f)) {       // defer-max (THR=8)
      float mnew = fmaxf(mrun, mx);
      float fac = __builtin_amdgcn_exp2f(mrun - mnew);
      lrun *= fac;
      f32x4 fv;
#pragma unroll
      for (int r = 0; r < 4; ++r) fv[r] = __shfl(fac, lg * 4 + r);
#pragma unroll
      for (int j = 0; j < 8; ++j) o[j] *= fv;
      mrun = mnew;
    }
    float rs = 0.0f;
#pragma unroll
    for (int nf = 0; nf < 2; ++nf) {
      bf16x4 pk;
#pragma unroll
      for (int r = 0; r < 4; ++r) {
        float p = __builtin_amdgcn_exp2f(sa[nf][r] - mrun);
        rs += p;
        pk[r] = (bf16)p;
      }
      *(bf16x4*)(Pw + l15 * 80 + nf * 32 + lg * 8) = pk;   // P[q=l15][k], padded rows
    }
    rs += __shfl_xor(rs, 16);
    rs += __shfl_xor(rs, 32);
    lrun += rs;

    // O += P V : A = P (row q=l15, k-octet lg), B = Vt rows d
    bf16x8 pa = *(const bf16x8*)(Pw + l15 * 80 + lg * 16);
#pragma unroll
    for (int nf2 = 0; nf2 < 8; ++nf2) {
      int d = nf2 * 16 + l15;
      int slot = lg ^ ((d >> 1) & 3);
      bf16x8 vb = *(const bf16x8*)(Vt + d * 64 + slot * 16);
      o[nf2] = MFMA_BF16(pa, vb, o[nf2]);
    }
    __syncthreads();
  }

  // epilogue: O /= l ; O rows q=lg*4+r, col d=nf2*16+l15
  f32x4 linv;
#pragma unroll
  for (int r = 0; r < 4; ++r) linv[r] = 1.0f / __shfl(lrun, lg * 4 + r);
#pragma unroll
  for (int j = 0; j < 8; ++j)
#pragma unroll
    for (int r = 0; r < 4; ++r) {
      size_t row = (size_t)(b * 2048 + q0 + lg * 4 + r);
      AO[row * 2048 + h * 128 + j * 16 + l15] = (bf16)(o[j][r] * linv[r]);
    }
}

// ------------------------------------------------------------------
extern "C" void kernel_launch(void* const* d_in, const int* in_sizes, int n_in,
                              void* d_out, int out_size, void* d_ws, size_t ws_size,
                              hipStream_t stream) {
  const float* hs   = (const float*)d_in[0];
  const float* cosb = (const float*)d_in[1];
  const float* sinb = (const float*)d_in[2];
  const float* Wq   = (const float*)d_in[3];
  const float* Wk   = (const float*)d_in[4];
  const float* Wv   = (const float*)d_in[5];
  const float* Wo   = (const float*)d_in[6];
  float* Out = (float*)d_out;

  char* ws = (char*)d_ws;
  size_t off = 0;
  auto alloc = [&](size_t bytes) { char* p = ws + off; off += bytes; return p; };
  bf16* Xbf = (bf16*)alloc((size_t)4096 * 2048 * 2);
  bf16* Wtq = (bf16*)alloc((size_t)2048 * 2048 * 2);
  bf16* Wtk = (bf16*)alloc((size_t)512 * 2048 * 2);
  bf16* Wtv = (bf16*)alloc((size_t)512 * 2048 * 2);
  bf16* Wto = (bf16*)alloc((size_t)2048 * 2048 * 2);
  bf16* Qb  = (bf16*)alloc((size_t)4096 * 2048 * 2);
  bf16* Kb  = (bf16*)alloc((size_t)4096 * 512 * 2);
  bf16* Vb  = (bf16*)alloc((size_t)4096 * 512 * 2);
  bf16* Vtb = (bf16*)alloc((size_t)4096 * 512 * 2);
  bf16* AO  = (bf16*)alloc((size_t)4096 * 2048 * 2);

  const float SCLQ = 0.08838834764831845f * 1.4426950408889634f;

  dim3 tb(32, 8);
  k_cvt_bf16<<<8192, 256, 0, stream>>>(hs, Xbf, 2097152);
  k_transpose_w4<<<dim3(64, 64, 4), tb, 0, stream>>>(Wq, Wk, Wv, Wo, Wtq, Wtk, Wtv, Wto);
  k_gemm_qkv<<<dim3(32, 24), 256, 0, stream>>>(Xbf, Wtq, Wtk, Wtv, Qb, Kb, Vb,
                                               cosb, sinb, SCLQ);
  k_transpose_v<<<dim3(64, 16, 2), tb, 0, stream>>>(Vb, Vtb);
  k_fattn<<<1024, 256, 0, stream>>>(Qb, Kb, Vtb, AO);
  k_gemm_o<<<dim3(32, 16), 256, 0, stream>>>(AO, Wto, Out);
}

// Round 7
// 202.104 us; speedup vs baseline: 4.3579x; 1.0024x over previous
//
#include <hip/hip_runtime.h>
#include <hip/hip_bf16.h>

// Attention layer: B=2, S=2048, H=2048, NH=16, NKV=4, HD=128, N_REP=4
// cvt X->bf16; merged weight transpose; fused QKV GEMM with RoPE epilogue and
// V-transpose epilogue; single-strip causal flash attention (KVBLK=32, dbuf
// glds, 4 blocks/CU, longest-first dispatch, setprio); O-proj GEMM (f32 out).

typedef __bf16 bf16;
typedef __bf16 bf16x8 __attribute__((ext_vector_type(8)));
typedef __bf16 bf16x4 __attribute__((ext_vector_type(4)));
typedef float  f32x4  __attribute__((ext_vector_type(4)));

#define MFMA_BF16(a, b, c) __builtin_amdgcn_mfma_f32_16x16x32_bf16((a), (b), (c), 0, 0, 0)

__device__ __forceinline__ void glds16(const bf16* g, char* l) {
  __builtin_amdgcn_global_load_lds((__attribute__((address_space(1))) const void*)g,
                                   (__attribute__((address_space(3))) void*)l, 16, 0, 0);
}

// ------------------------------------------------------------------
__global__ __launch_bounds__(256) void k_cvt_bf16(const float* __restrict__ in,
                                                  bf16* __restrict__ out, int n4) {
  int i = blockIdx.x * 256 + threadIdx.x;
  if (i < n4) {
    float4 v = ((const float4*)in)[i];
    bf16x4 o;
    o[0] = (bf16)v.x; o[1] = (bf16)v.y; o[2] = (bf16)v.z; o[3] = (bf16)v.w;
    ((bf16x4*)out)[i] = o;
  }
}

// ------------------------------------------------------------------
// Merged weight transpose: W [Kd=2048][N] f32 -> Wt [N][2048] bf16.
// z: 0=Wq(N=2048) 1=Wo(N=2048) 2=Wk(N=512) 3=Wv(N=512).
__global__ __launch_bounds__(256) void k_transpose_w4(const float* __restrict__ Wq,
                                                      const float* __restrict__ Wk,
                                                      const float* __restrict__ Wv,
                                                      const float* __restrict__ Wo,
                                                      bf16* __restrict__ Wtq,
                                                      bf16* __restrict__ Wtk,
                                                      bf16* __restrict__ Wtv,
                                                      bf16* __restrict__ Wto) {
  int z = blockIdx.z;
  const float* W; bf16* Wt; int N;
  if (z == 0)      { W = Wq; Wt = Wtq; N = 2048; }
  else if (z == 1) { W = Wo; Wt = Wto; N = 2048; }
  else if (z == 2) { W = Wk; Wt = Wtk; N = 512; }
  else             { W = Wv; Wt = Wtv; N = 512; }
  int nb = blockIdx.y * 32;
  if (nb >= N) return;
  __shared__ float tile[32][33];
  int tx = threadIdx.x, ty = threadIdx.y;
  int kb = blockIdx.x * 32;
#pragma unroll
  for (int i = 0; i < 4; ++i)
    tile[ty + i * 8][tx] = W[(size_t)(kb + ty + i * 8) * N + nb + tx];
  __syncthreads();
#pragma unroll
  for (int i = 0; i < 4; ++i)
    Wt[(size_t)(nb + ty + i * 8) * 2048 + kb + tx] = (bf16)tile[tx][ty + i * 8];
}

// ------------------------------------------------------------------
// GEMM 128x128 tile, BK=64, global_load_lds staging (inverse-swizzled source),
// double-buffered LDS, one barrier per K-step.
// rope_scl != 0: fused RoPE epilogue (cols are one head; pairs (d,d+64) =
// acc[nf], acc[nf+4] in the SAME lane).
// vtr != nullptr: V-transpose epilogue — write Vt[(b*4+vkv)*128+d][2048]
// via swizzled LDS bounce instead of the normal C store.
template <typename OUT>
__device__ void gemm_block(const bf16* __restrict__ A, const bf16* __restrict__ Bt,
                           OUT* __restrict__ C, int K, int ldc,
                           int rbase, int cbase, char* sm,
                           float rope_scl, const float* __restrict__ cosb,
                           const float* __restrict__ sinb,
                           bf16* __restrict__ vtr, int vkv) {
  const int tid = threadIdx.x;
  const int lane = tid & 63, wid = tid >> 6;
  const int l15 = lane & 15, lg = lane >> 4;
  char* Asm = sm;            // 2 x 16KB : [128][128B] swizzled
  char* Bsm = sm + 32768;    // 2 x 16KB

  f32x4 acc[2][8];
#pragma unroll
  for (int i = 0; i < 2; ++i)
#pragma unroll
    for (int j = 0; j < 8; ++j)
#pragma unroll
      for (int r = 0; r < 4; ++r) acc[i][j][r] = 0.0f;

  const int ob = wid * 4096 + lane * 16;
  auto stage = [&](int buf, int kb) {
#pragma unroll
    for (int c = 0; c < 4; ++c) {
      int o = ob + c * 1024;
      int r = o >> 7;
      int cc = ((o >> 4) & 7) ^ (r & 7);
      int dst = wid * 4096 + c * 1024 + buf * 16384;   // wave-uniform LDS base
      glds16(A + (size_t)(rbase + r) * K + kb + cc * 8, Asm + dst);
      glds16(Bt + (size_t)(cbase + r) * K + kb + cc * 8, Bsm + dst);
    }
  };

  stage(0, 0);
  __syncthreads();
  const int nk = K >> 6;
  for (int t = 0; t < nk; ++t) {
    if (t + 1 < nk) stage((t + 1) & 1, (t + 1) << 6);
    const char* At  = Asm + (t & 1) * 16384;
    const char* Bti = Bsm + (t & 1) * 16384;
#pragma unroll
    for (int ks = 0; ks < 2; ++ks) {
      bf16x8 a[2], b[8];
#pragma unroll
      for (int rf = 0; rf < 2; ++rf) {
        int r = wid * 32 + rf * 16 + l15;
        int slot = (ks * 4 + lg) ^ (r & 7);
        a[rf] = *(const bf16x8*)(At + r * 128 + slot * 16);
      }
#pragma unroll
      for (int nf = 0; nf < 8; ++nf) {
        int n = nf * 16 + l15;
        int slot = (ks * 4 + lg) ^ (n & 7);
        b[nf] = *(const bf16x8*)(Bti + n * 128 + slot * 16);
      }
#pragma unroll
      for (int rf = 0; rf < 2; ++rf)
#pragma unroll
        for (int nf = 0; nf < 8; ++nf)
          acc[rf][nf] = MFMA_BF16(a[rf], b[nf], acc[rf][nf]);
    }
    __syncthreads();
  }

  if (rope_scl != 0.0f) {
#pragma unroll
    for (int rf = 0; rf < 2; ++rf)
#pragma unroll
      for (int r = 0; r < 4; ++r) {
        int s = (rbase + wid * 32 + rf * 16 + lg * 4 + r) & 2047;
#pragma unroll
        for (int nf = 0; nf < 4; ++nf) {
          int d = nf * 16 + l15;
          float v0 = acc[rf][nf][r], v1 = acc[rf][nf + 4][r];
          float c0 = cosb[s * 128 + d],      c1 = cosb[s * 128 + d + 64];
          float s0 = sinb[s * 128 + d],      s1 = sinb[s * 128 + d + 64];
          acc[rf][nf][r]     = (v0 * c0 - v1 * s0) * rope_scl;
          acc[rf][nf + 4][r] = (v1 * c1 + v0 * s1) * rope_scl;
        }
      }
  }

  if (vtr != nullptr) {
    // Transpose epilogue: acc = C[s][d], s local 0..127, d local 0..127.
    // LDS [d][128 s] bf16 rows of 256B; swizzle byte = d*256 + (s*2 ^ ((d&15)<<4)).
#pragma unroll
    for (int rf = 0; rf < 2; ++rf)
#pragma unroll
      for (int nf = 0; nf < 8; ++nf) {
        int s0 = wid * 32 + rf * 16 + lg * 4;   // aligned 4-run, survives XOR (bits>=4)
        int d = nf * 16 + l15;
        bf16x4 pk;
#pragma unroll
        for (int r = 0; r < 4; ++r) pk[r] = (bf16)acc[rf][nf][r];
        *(bf16x4*)(sm + d * 256 + ((s0 * 2) ^ ((d & 15) << 4))) = pk;
      }
    __syncthreads();
    const int b4 = (rbase >> 11) * 4;
    const int scol = rbase & 2047;
    const int so = tid & 15;
#pragma unroll
    for (int i = 0; i < 8; ++i) {
      int d = (tid >> 4) + i * 16;
      bf16x8 v = *(const bf16x8*)(sm + d * 256 + ((so * 16) ^ ((d & 15) << 4)));
      *(bf16x8*)(vtr + (size_t)((b4 + vkv) * 128 + d) * 2048 + scol + so * 8) = v;
    }
    return;
  }

#pragma unroll
  for (int rf = 0; rf < 2; ++rf)
#pragma unroll
    for (int nf = 0; nf < 8; ++nf)
#pragma unroll
      for (int r = 0; r < 4; ++r) {
        int row = rbase + wid * 32 + rf * 16 + lg * 4 + r;
        int col = cbase + nf * 16 + l15;
        C[(size_t)row * ldc + col] = (OUT)acc[rf][nf][r];
      }
}

__global__ __launch_bounds__(256, 2) void k_gemm_qkv(const bf16* __restrict__ X,
                                                     const bf16* __restrict__ Wtq,
                                                     const bf16* __restrict__ Wtk,
                                                     const bf16* __restrict__ Wtv,
                                                     bf16* __restrict__ Q,
                                                     bf16* __restrict__ Ko,
                                                     bf16* __restrict__ Vt,
                                                     const float* __restrict__ cosb,
                                                     const float* __restrict__ sinb,
                                                     float sclq) {
  __shared__ alignas(16) char sm[65536];
  int nb = blockIdx.y;
  int rbase = blockIdx.x * 128;
  if (nb < 16) {
    gemm_block<bf16>(X, Wtq, Q, 2048, 2048, rbase, nb * 128, sm, sclq, cosb, sinb,
                     nullptr, 0);
  } else if (nb < 20) {
    gemm_block<bf16>(X, Wtk, Ko, 2048, 512, rbase, (nb - 16) * 128, sm, 1.0f, cosb, sinb,
                     nullptr, 0);
  } else {
    gemm_block<bf16>(X, Wtv, (bf16*)nullptr, 2048, 512, rbase, (nb - 20) * 128, sm,
                     0.0f, nullptr, nullptr, Vt, nb - 20);
  }
}

__global__ __launch_bounds__(256, 2) void k_gemm_o(const bf16* __restrict__ AO,
                                                   const bf16* __restrict__ Wto,
                                                   float* __restrict__ Out) {
  __shared__ alignas(16) char sm[65536];
  gemm_block<float>(AO, Wto, Out, 2048, 2048, blockIdx.x * 128, blockIdx.y * 128, sm,
                    0.0f, nullptr, nullptr, nullptr, 0);
}

// ------------------------------------------------------------------
// Single-strip causal flash attention. Block = one strip of 64 q-rows
// (4 waves x 16 rows), KVBLK=32, K/V double-buffered via global_load_lds,
// 1 barrier/tile. LDS 37.9KB -> 4 blocks/CU; launch_bounds(256,4) caps VGPR
// at 128. Grid 1024: wg&7 = (b,kv) XCD group; strips longest-first (LPT).
__global__ __launch_bounds__(256, 4) void k_fattn(const bf16* __restrict__ Qg,
                                                  const bf16* __restrict__ Kg,
                                                  const bf16* __restrict__ Vtg,
                                                  bf16* __restrict__ AO) {
  __shared__ alignas(16) char sm[37888];
  // [0,16384): K 2x(32x256B) ; [16384,32768): Vt 2x(128x64B) ; [32768,37888): P 4x1280B
  const int lane = threadIdx.x & 63, wid = threadIdx.x >> 6;
  const int l15 = lane & 15, lg = lane >> 4;
  const int wg = blockIdx.x;
  const int grp = wg & 7;            // XCD-resident (b,kv) group
  const int b = grp >> 2, kv = grp & 3;
  const int inner = wg >> 3;         // 0..127
  const int h = kv * 4 + (inner & 3);
  const int strip = 31 - (inner >> 2);   // longest-first (LPT) dispatch
  const int q0 = strip * 64 + wid * 16;
  const int nt = 2 * (strip + 1);
  char* Pw = sm + 32768 + wid * 1280;    // [16 rows][80B] padded

  // Q fragments (B-operand of swapped QK^T): lane l15 = q-row, lg = d-octet
  bf16x8 qf[4];
#pragma unroll
  for (int kf = 0; kf < 4; ++kf)
    qf[kf] = *(const bf16x8*)(Qg + (size_t)(b * 2048 + q0 + l15) * 2048 + h * 128 + kf * 32 + lg * 8);

  f32x4 o[8];
#pragma unroll
  for (int j = 0; j < 8; ++j)
#pragma unroll
    for (int r = 0; r < 4; ++r) o[j][r] = 0.0f;
  float mrun = -3e38f, lrun = 0.0f;

  const bf16* ksrc[2];
  const bf16* vsrc[2];
  int kdst[2], vdst[2];
#pragma unroll
  for (int j = 0; j < 2; ++j) {
    int c = wid * 128 + j * 64 + lane;
    int kr = c >> 4, kslot = c & 15;
    int kcc = kslot ^ (kr & 15);
    ksrc[j] = Kg + (size_t)(b * 2048 + kr) * 512 + kv * 128 + kcc * 8;
    kdst[j] = wid * 2048 + j * 1024;
    int vr = c >> 2, vslot = c & 3;
    int vcc = vslot ^ ((vr >> 1) & 3);
    vsrc[j] = Vtg + (size_t)((b * 4 + kv) * 128 + vr) * 2048 + vcc * 8;
    vdst[j] = 16384 + wid * 2048 + j * 1024;
  }
  auto stageKV = [&](int buf) {
#pragma unroll
    for (int j = 0; j < 2; ++j) {
      glds16(ksrc[j], sm + buf * 8192 + kdst[j]);
      glds16(vsrc[j], sm + buf * 8192 + vdst[j]);
      ksrc[j] += 32 * 512;   // next 32 kv rows
      vsrc[j] += 32;         // next 32 seq cols
    }
  };

  stageKV(0);
  __syncthreads();

  for (int t = 0; t < nt; ++t) {
    const int kb = t << 5;
    if (t + 1 < nt) stageKV((t + 1) & 1);
    const char* Kt = sm + (t & 1) * 8192;
    const char* Vt = sm + 16384 + (t & 1) * 8192;

    // S^T = K Q^T : rows k = nf*16+lg*4+r, col q = l15
    f32x4 sa[2];
#pragma unroll
    for (int j = 0; j < 2; ++j)
#pragma unroll
      for (int r = 0; r < 4; ++r) sa[j][r] = 0.0f;
    __builtin_amdgcn_s_setprio(1);
#pragma unroll
    for (int kf = 0; kf < 4; ++kf) {
#pragma unroll
      for (int nf = 0; nf < 2; ++nf) {
        int slot = (kf * 4 + lg) ^ l15;
        bf16x8 bk = *(const bf16x8*)(Kt + (nf * 16 + l15) * 256 + slot * 16);
        sa[nf] = MFMA_BF16(bk, qf[kf], sa[nf]);
      }
    }
    __builtin_amdgcn_s_setprio(0);

    // causal mask
    if (kb + 31 > q0) {
      const int qi = q0 + l15;
#pragma unroll
      for (int nf = 0; nf < 2; ++nf)
#pragma unroll
        for (int r = 0; r < 4; ++r)
          if (kb + nf * 16 + lg * 4 + r > qi) sa[nf][r] = -3e38f;
    }

    // in-lane softmax (log2 units); row q=l15 split across 4 lg-lanes
    float mx = sa[0][0];
#pragma unroll
    for (int nf = 0; nf < 2; ++nf)
#pragma unroll
      for (int r = 0; r < 4; ++r) mx = fmaxf(mx, sa[nf][r]);
    mx = fmaxf(mx, __shfl_xor(mx, 16));
    mx = fmaxf(mx, __shfl_xor(mx, 32));
    if (!__all(mx - mrun <= 8.0f)) {       // defer-max (THR=8)
      float mnew = fmaxf(mrun, mx);
      float fac = __builtin_amdgcn_exp2f(mrun - mnew);
      lrun *= fac;
      f32x4 fv;
#pragma unroll
      for (int r = 0; r < 4; ++r) fv[r] = __shfl(fac, lg * 4 + r);
#pragma unroll
      for (int j = 0; j < 8; ++j) o[j] *= fv;
      mrun = mnew;
    }
    float rs = 0.0f;
#pragma unroll
    for (int nf = 0; nf < 2; ++nf) {
      bf16x4 pk;
#pragma unroll
      for (int r = 0; r < 4; ++r) {
        float p = __builtin_amdgcn_exp2f(sa[nf][r] - mrun);
        rs += p;
        pk[r] = (bf16)p;
      }
      *(bf16x4*)(Pw + l15 * 80 + nf * 32 + lg * 8) = pk;   // P[q=l15][k], padded rows
    }
    rs += __shfl_xor(rs, 16);
    rs += __shfl_xor(rs, 32);
    lrun += rs;

    // O += P V : A = P (row q=l15, k-octet lg), B = Vt rows d
    bf16x8 pa = *(const bf16x8*)(Pw + l15 * 80 + lg * 16);
    __builtin_amdgcn_s_setprio(1);
#pragma unroll
    for (int nf2 = 0; nf2 < 8; ++nf2) {
      int d = nf2 * 16 + l15;
      int slot = lg ^ ((d >> 1) & 3);
      bf16x8 vb = *(const bf16x8*)(Vt + d * 64 + slot * 16);
      o[nf2] = MFMA_BF16(pa, vb, o[nf2]);
    }
    __builtin_amdgcn_s_setprio(0);
    __syncthreads();
  }

  // epilogue: O /= l ; O rows q=lg*4+r, col d=nf2*16+l15
  f32x4 linv;
#pragma unroll
  for (int r = 0; r < 4; ++r) linv[r] = 1.0f / __shfl(lrun, lg * 4 + r);
#pragma unroll
  for (int j = 0; j < 8; ++j)
#pragma unroll
    for (int r = 0; r < 4; ++r) {
      size_t row = (size_t)(b * 2048 + q0 + lg * 4 + r);
      AO[row * 2048 + h * 128 + j * 16 + l15] = (bf16)(o[j][r] * linv[r]);
    }
}

// ------------------------------------------------------------------
extern "C" void kernel_launch(void* const* d_in, const int* in_sizes, int n_in,
                              void* d_out, int out_size, void* d_ws, size_t ws_size,
                              hipStream_t stream) {
  const float* hs   = (const float*)d_in[0];
  const float* cosb = (const float*)d_in[1];
  const float* sinb = (const float*)d_in[2];
  const float* Wq   = (const float*)d_in[3];
  const float* Wk   = (const float*)d_in[4];
  const float* Wv   = (const float*)d_in[5];
  const float* Wo   = (const float*)d_in[6];
  float* Out = (float*)d_out;

  char* ws = (char*)d_ws;
  size_t off = 0;
  auto alloc = [&](size_t bytes) { char* p = ws + off; off += bytes; return p; };
  bf16* Xbf = (bf16*)alloc((size_t)4096 * 2048 * 2);
  bf16* Wtq = (bf16*)alloc((size_t)2048 * 2048 * 2);
  bf16* Wtk = (bf16*)alloc((size_t)512 * 2048 * 2);
  bf16* Wtv = (bf16*)alloc((size_t)512 * 2048 * 2);
  bf16* Wto = (bf16*)alloc((size_t)2048 * 2048 * 2);
  bf16* Qb  = (bf16*)alloc((size_t)4096 * 2048 * 2);
  bf16* Kb  = (bf16*)alloc((size_t)4096 * 512 * 2);
  bf16* Vtb = (bf16*)alloc((size_t)4096 * 512 * 2);
  bf16* AO  = (bf16*)alloc((size_t)4096 * 2048 * 2);

  const float SCLQ = 0.08838834764831845f * 1.4426950408889634f;

  dim3 tb(32, 8);
  k_cvt_bf16<<<8192, 256, 0, stream>>>(hs, Xbf, 2097152);
  k_transpose_w4<<<dim3(64, 64, 4), tb, 0, stream>>>(Wq, Wk, Wv, Wo, Wtq, Wtk, Wtv, Wto);
  k_gemm_qkv<<<dim3(32, 24), 256, 0, stream>>>(Xbf, Wtq, Wtk, Wtv, Qb, Kb, Vtb,
                                               cosb, sinb, SCLQ);
  k_fattn<<<1024, 256, 0, stream>>>(Qb, Kb, Vtb, AO);
  k_gemm_o<<<dim3(32, 16), 256, 0, stream>>>(AO, Wto, Out);
}